// Round 2
// baseline (1416.200 us; speedup 1.0000x reference)
//
#include <hip/hip_runtime.h>

#define NNODE 16384
#define IN_F  256
#define OUT_F 128
#define ROWS  4      // one row per wave, 4 waves per block
#define MAXNB 256    // neighbor-list capacity (mean ~33, max ~60)

// Block = 256 threads = 4 waves; wave w owns row row0+w.
// Phase A: wave scans its A-row (float4, 4 loads in flight) -> LDS index list.
// Phase B: wave gathers H rows; float4/lane spans all 256 features in one load.
// Phase C: all 256 threads compute out = agg @ W^T with float4 W loads and
//          broadcast ds_read_b128 for agg.
__global__ __launch_bounds__(256, 4) void gcn_fused_kernel(
    const float* __restrict__ A,
    const float* __restrict__ H,
    const float* __restrict__ W,
    float* __restrict__ out)
{
    __shared__ int   s_cnt[ROWS];
    __shared__ int   s_idx[ROWS][MAXNB];
    __shared__ float s_agg[ROWS][IN_F];
    __shared__ float s_part[OUT_F][ROWS + 1];   // +1 pad: kill 8-way bank conflict

    const int t    = threadIdx.x;
    const int wave = t >> 6;
    const int lane = t & 63;
    const int row0 = blockIdx.x * ROWS;

    if (t < ROWS) s_cnt[t] = 0;
    __syncthreads();

    // ---- Phase A: per-wave coalesced scan, 4 float4 loads in flight ----
    const float4* A4 = reinterpret_cast<const float4*>(
        A + (size_t)(row0 + wave) * NNODE);

#define PROC(v, kk)                                                              \
    {                                                                            \
        int j = ((kk) * 64 + lane) * 4;                                          \
        if ((v).x != 0.f) { int p = atomicAdd(&s_cnt[wave], 1); if (p < MAXNB) s_idx[wave][p] = j;     } \
        if ((v).y != 0.f) { int p = atomicAdd(&s_cnt[wave], 1); if (p < MAXNB) s_idx[wave][p] = j + 1; } \
        if ((v).z != 0.f) { int p = atomicAdd(&s_cnt[wave], 1); if (p < MAXNB) s_idx[wave][p] = j + 2; } \
        if ((v).w != 0.f) { int p = atomicAdd(&s_cnt[wave], 1); if (p < MAXNB) s_idx[wave][p] = j + 3; } \
    }

    for (int k = 0; k < NNODE / 4 / 64; k += 4) {        // 16 outer iterations
        float4 v0 = A4[(k + 0) * 64 + lane];
        float4 v1 = A4[(k + 1) * 64 + lane];
        float4 v2 = A4[(k + 2) * 64 + lane];
        float4 v3 = A4[(k + 3) * 64 + lane];
        PROC(v0, k + 0) PROC(v1, k + 1) PROC(v2, k + 2) PROC(v3, k + 3)
    }
#undef PROC

    // ---- Phase B: per-wave gather (no cross-wave barrier needed) ----
    const float4* H4 = reinterpret_cast<const float4*>(H);
    int cnt = s_cnt[wave];
    if (cnt > MAXNB) cnt = MAXNB;

    float4 a0 = {0,0,0,0}, a1 = a0, a2 = a0, a3 = a0;
    int k = 0;
    for (; k + 4 <= cnt; k += 4) {
        int j0 = s_idx[wave][k + 0], j1 = s_idx[wave][k + 1];
        int j2 = s_idx[wave][k + 2], j3 = s_idx[wave][k + 3];
        float4 v0 = H4[(size_t)j0 * 64 + lane];
        float4 v1 = H4[(size_t)j1 * 64 + lane];
        float4 v2 = H4[(size_t)j2 * 64 + lane];
        float4 v3 = H4[(size_t)j3 * 64 + lane];
        a0.x += v0.x; a0.y += v0.y; a0.z += v0.z; a0.w += v0.w;
        a1.x += v1.x; a1.y += v1.y; a1.z += v1.z; a1.w += v1.w;
        a2.x += v2.x; a2.y += v2.y; a2.z += v2.z; a2.w += v2.w;
        a3.x += v3.x; a3.y += v3.y; a3.z += v3.z; a3.w += v3.w;
    }
    for (; k < cnt; ++k) {
        int j = s_idx[wave][k];
        float4 v = H4[(size_t)j * 64 + lane];
        a0.x += v.x; a0.y += v.y; a0.z += v.z; a0.w += v.w;
    }
    const float inv = 1.f / (float)(cnt + 1);
    float4 agg;
    agg.x = (a0.x + a1.x + a2.x + a3.x) * inv;
    agg.y = (a0.y + a1.y + a2.y + a3.y) * inv;
    agg.z = (a0.z + a1.z + a2.z + a3.z) * inv;
    agg.w = (a0.w + a1.w + a2.w + a3.w) * inv;
    *reinterpret_cast<float4*>(&s_agg[wave][lane * 4]) = agg;
    __syncthreads();

    // ---- Phase C: out[row, o] = dot(agg[row,:], W[o,:]) ----
    const int o    = t & (OUT_F - 1);
    const int half = t >> 7;                       // 0 or 1
    float acc[ROWS] = {0.f, 0.f, 0.f, 0.f};

    const float4* W4 = reinterpret_cast<const float4*>(
        W + (size_t)o * IN_F + half * (IN_F / 2));
    for (int kk = 0; kk < IN_F / 2 / 4; ++kk) {    // 32 iterations
        float4 wv = W4[kk];
        const int c = half * (IN_F / 2) + kk * 4;
        #pragma unroll
        for (int r = 0; r < ROWS; ++r) {
            float4 g = *reinterpret_cast<const float4*>(&s_agg[r][c]);  // broadcast
            acc[r] += wv.x * g.x + wv.y * g.y + wv.z * g.z + wv.w * g.w;
        }
    }

    if (half == 1) {
        #pragma unroll
        for (int r = 0; r < ROWS; ++r) s_part[o][r] = acc[r];
    }
    __syncthreads();
    if (half == 0) {
        #pragma unroll
        for (int r = 0; r < ROWS; ++r)
            out[(size_t)(row0 + r) * OUT_F + o] = acc[r] + s_part[o][r];
    }
}

extern "C" void kernel_launch(void* const* d_in, const int* in_sizes, int n_in,
                              void* d_out, int out_size, void* d_ws, size_t ws_size,
                              hipStream_t stream) {
    const float* A = (const float*)d_in[0];   // [N, N]
    const float* H = (const float*)d_in[1];   // [N, IN_F]
    const float* W = (const float*)d_in[2];   // [OUT_F, IN_F]
    float* out = (float*)d_out;               // [N, OUT_F]

    dim3 grid(NNODE / ROWS);                  // 4096 blocks
    dim3 block(256);
    gcn_fused_kernel<<<grid, block, 0, stream>>>(A, H, W, out);
}

// Round 4
// 1356.060 us; speedup vs baseline: 1.0443x; 1.0443x over previous
//
#include <hip/hip_runtime.h>

#define NNODE 16384
#define IN_F  256
#define OUT_F 128
#define ROWS  4      // one row per wave, 4 waves per block
#define MAXNB 256    // neighbor-list capacity (mean ~33, max ~60)

typedef float vfloat4 __attribute__((ext_vector_type(4)));  // native clang vector
                                                            // (NT builtins require it)

// Block = 256 threads = 4 waves; wave w owns row row0+w.
// Phase A: wave scans its A-row with NON-TEMPORAL float4 loads (8 in flight)
//          so the 1 GiB A stream doesn't evict H from L2/L3.
// Phase B: wave gathers H rows (cached); float4/lane spans all 256 features.
// Phase C: out = agg @ W^T with float4 W loads + broadcast ds_read_b128.
__global__ __launch_bounds__(256, 4) void gcn_fused_kernel(
    const float* __restrict__ A,
    const float* __restrict__ H,
    const float* __restrict__ W,
    float* __restrict__ out)
{
    __shared__ int   s_cnt[ROWS];
    __shared__ int   s_idx[ROWS][MAXNB];
    __shared__ float s_agg[ROWS][IN_F];
    __shared__ float s_part[OUT_F][ROWS + 1];   // +1 pad: kill bank conflicts

    const int t    = threadIdx.x;
    const int wave = t >> 6;
    const int lane = t & 63;
    const int row0 = blockIdx.x * ROWS;

    if (t < ROWS) s_cnt[t] = 0;
    __syncthreads();

    // ---- Phase A: per-wave coalesced non-temporal scan, 8 loads in flight ----
    const vfloat4* A4 = reinterpret_cast<const vfloat4*>(
        A + (size_t)(row0 + wave) * NNODE);

#define PROC(v, kk)                                                              \
    {                                                                            \
        int j = ((kk) * 64 + lane) * 4;                                          \
        if ((v).x != 0.f) { int p = atomicAdd(&s_cnt[wave], 1); if (p < MAXNB) s_idx[wave][p] = j;     } \
        if ((v).y != 0.f) { int p = atomicAdd(&s_cnt[wave], 1); if (p < MAXNB) s_idx[wave][p] = j + 1; } \
        if ((v).z != 0.f) { int p = atomicAdd(&s_cnt[wave], 1); if (p < MAXNB) s_idx[wave][p] = j + 2; } \
        if ((v).w != 0.f) { int p = atomicAdd(&s_cnt[wave], 1); if (p < MAXNB) s_idx[wave][p] = j + 3; } \
    }

    for (int k = 0; k < NNODE / 4 / 64; k += 8) {        // 8 outer iterations
        vfloat4 v0 = __builtin_nontemporal_load(&A4[(k + 0) * 64 + lane]);
        vfloat4 v1 = __builtin_nontemporal_load(&A4[(k + 1) * 64 + lane]);
        vfloat4 v2 = __builtin_nontemporal_load(&A4[(k + 2) * 64 + lane]);
        vfloat4 v3 = __builtin_nontemporal_load(&A4[(k + 3) * 64 + lane]);
        vfloat4 v4 = __builtin_nontemporal_load(&A4[(k + 4) * 64 + lane]);
        vfloat4 v5 = __builtin_nontemporal_load(&A4[(k + 5) * 64 + lane]);
        vfloat4 v6 = __builtin_nontemporal_load(&A4[(k + 6) * 64 + lane]);
        vfloat4 v7 = __builtin_nontemporal_load(&A4[(k + 7) * 64 + lane]);
        PROC(v0, k + 0) PROC(v1, k + 1) PROC(v2, k + 2) PROC(v3, k + 3)
        PROC(v4, k + 4) PROC(v5, k + 5) PROC(v6, k + 6) PROC(v7, k + 7)
    }
#undef PROC

    // ---- Phase B: per-wave gather from (hopefully cache-resident) H ----
    const float4* H4 = reinterpret_cast<const float4*>(H);
    int cnt = s_cnt[wave];
    if (cnt > MAXNB) cnt = MAXNB;

    float4 a0 = {0,0,0,0}, a1 = a0, a2 = a0, a3 = a0;
    int k = 0;
    for (; k + 4 <= cnt; k += 4) {
        int j0 = s_idx[wave][k + 0], j1 = s_idx[wave][k + 1];
        int j2 = s_idx[wave][k + 2], j3 = s_idx[wave][k + 3];
        float4 v0 = H4[(size_t)j0 * 64 + lane];
        float4 v1 = H4[(size_t)j1 * 64 + lane];
        float4 v2 = H4[(size_t)j2 * 64 + lane];
        float4 v3 = H4[(size_t)j3 * 64 + lane];
        a0.x += v0.x; a0.y += v0.y; a0.z += v0.z; a0.w += v0.w;
        a1.x += v1.x; a1.y += v1.y; a1.z += v1.z; a1.w += v1.w;
        a2.x += v2.x; a2.y += v2.y; a2.z += v2.z; a2.w += v2.w;
        a3.x += v3.x; a3.y += v3.y; a3.z += v3.z; a3.w += v3.w;
    }
    for (; k < cnt; ++k) {
        int j = s_idx[wave][k];
        float4 v = H4[(size_t)j * 64 + lane];
        a0.x += v.x; a0.y += v.y; a0.z += v.z; a0.w += v.w;
    }
    const float inv = 1.f / (float)(cnt + 1);
    float4 agg;
    agg.x = (a0.x + a1.x + a2.x + a3.x) * inv;
    agg.y = (a0.y + a1.y + a2.y + a3.y) * inv;
    agg.z = (a0.z + a1.z + a2.z + a3.z) * inv;
    agg.w = (a0.w + a1.w + a2.w + a3.w) * inv;
    *reinterpret_cast<float4*>(&s_agg[wave][lane * 4]) = agg;
    __syncthreads();

    // ---- Phase C: out[row, o] = dot(agg[row,:], W[o,:]) ----
    const int o    = t & (OUT_F - 1);
    const int half = t >> 7;                       // 0 or 1
    float acc[ROWS] = {0.f, 0.f, 0.f, 0.f};

    const float4* W4 = reinterpret_cast<const float4*>(
        W + (size_t)o * IN_F + half * (IN_F / 2));
    for (int kk = 0; kk < IN_F / 2 / 4; ++kk) {    // 32 iterations
        float4 wv = W4[kk];
        const int c = half * (IN_F / 2) + kk * 4;
        #pragma unroll
        for (int r = 0; r < ROWS; ++r) {
            float4 g = *reinterpret_cast<const float4*>(&s_agg[r][c]);  // broadcast
            acc[r] += wv.x * g.x + wv.y * g.y + wv.z * g.z + wv.w * g.w;
        }
    }

    if (half == 1) {
        #pragma unroll
        for (int r = 0; r < ROWS; ++r) s_part[o][r] = acc[r];
    }
    __syncthreads();
    if (half == 0) {
        #pragma unroll
        for (int r = 0; r < ROWS; ++r)
            __builtin_nontemporal_store(acc[r] + s_part[o][r],
                                        &out[(size_t)(row0 + r) * OUT_F + o]);
    }
}

extern "C" void kernel_launch(void* const* d_in, const int* in_sizes, int n_in,
                              void* d_out, int out_size, void* d_ws, size_t ws_size,
                              hipStream_t stream) {
    const float* A = (const float*)d_in[0];   // [N, N]
    const float* H = (const float*)d_in[1];   // [N, IN_F]
    const float* W = (const float*)d_in[2];   // [OUT_F, IN_F]
    float* out = (float*)d_out;               // [N, OUT_F]

    dim3 grid(NNODE / ROWS);                  // 4096 blocks
    dim3 block(256);
    gcn_fused_kernel<<<grid, block, 0, stream>>>(A, H, W, out);
}